// Round 6
// baseline (715.404 us; speedup 1.0000x reference)
//
#include <hip/hip_runtime.h>
#include <math.h>

#define D 128
#define CHK 64
#define NCHUNK 128
#define LSEQ 8192
#define B_LR 0.005f
#define M_LR 0.01f

typedef float f2 __attribute__((ext_vector_type(2)));

// packed fp32 (VOP3P) helpers; accumulate forms are tied in-place (no copies)
__device__ __forceinline__ f2 pk_mul(f2 a, f2 b){ f2 d; asm("v_pk_mul_f32 %0, %1, %2" : "=v"(d) : "v"(a), "v"(b)); return d; }
__device__ __forceinline__ void pk_fma_acc(f2 &acc, f2 a, f2 b){ asm("v_pk_fma_f32 %0, %1, %2, %0" : "+v"(acc) : "v"(a), "v"(b)); }

template<int C>
__device__ __forceinline__ float dppx(float x){
  return __int_as_float(__builtin_amdgcn_update_dpp(0, __float_as_int(x), C, 0xF, 0xF, true));
}
__device__ __forceinline__ void pl32swap(float &a, float &b){ asm("v_permlane32_swap_b32 %0, %1" : "+v"(a), "+v"(b)); }
__device__ __forceinline__ void pl16swap(float &a, float &b){ asm("v_permlane16_swap_b32 %0, %1" : "+v"(a), "+v"(b)); }

// transpose-reduce: input a[64] per lane; lane L returns sum over all 64 lanes of a[L].
// Same dataflow as rounds 1-4 (verified); swap stages now operate IN-PLACE on the
// array elements so the allocator has no reason to emit marshaling copies.
__device__ __forceinline__ float butterfly64(float* a, int lane){
  #pragma unroll
  for (int t = 0; t < 32; ++t){ pl32swap(a[t], a[t+32]); a[t] = a[t] + a[t+32]; }
  #pragma unroll
  for (int t = 0; t < 16; ++t){ pl16swap(a[t], a[t+16]); a[t] = a[t] + a[t+16]; }
  const bool h8 = (lane & 8) != 0, h4 = (lane & 4) != 0, h2 = (lane & 2) != 0, h1 = (lane & 1) != 0;
  #pragma unroll
  for (int t = 0; t < 8; ++t){
    float send = h8 ? a[t] : a[t+8];
    float keep = h8 ? a[t+8] : a[t];
    a[t] = keep + dppx<0x128>(send);                  // row_ror:8 == lane^8
  }
  #pragma unroll
  for (int t = 0; t < 4; ++t){
    float send = h4 ? a[t] : a[t+4];
    float keep = h4 ? a[t+4] : a[t];
    a[t] = keep + __int_as_float(__builtin_amdgcn_ds_swizzle(__float_as_int(send), 0x101F)); // lane^4
  }
  #pragma unroll
  for (int t = 0; t < 2; ++t){
    float send = h2 ? a[t] : a[t+2];
    float keep = h2 ? a[t+2] : a[t];
    a[t] = keep + dppx<0x4E>(send);                   // quad_perm xor2
  }
  float send = h1 ? a[0] : a[1];
  float keep = h1 ? a[1] : a[0];
  return keep + dppx<0xB1>(send);                     // quad_perm xor1
}

__device__ __forceinline__ void gl_lds16(const float* g, float* l){
  __builtin_amdgcn_global_load_lds((const __attribute__((address_space(1))) float*)g,
                                   (__attribute__((address_space(3))) float*)l, 16, 0, 0);
}

__global__ __launch_bounds__(512, 1) void lfltm_fwd(
    const float* __restrict__ X,
    const float* __restrict__ init_mem,
    const float* __restrict__ init_opt,
    float* __restrict__ out)
{
  __shared__ float xs[2][CHK * D];       // 64 KiB: double-buffered x chunk, linear [c][j]
  __shared__ f2 es2[8][CHK];             //  4 KiB: per-wave e broadcast, PRE-SPLATTED {e,e}
  __shared__ float outs[2][CHK * 9];     // out staging, pad 9 (2-way bank alias only)

  const int tid  = threadIdx.x;
  const int w    = tid >> 6;             // wave -> row within group
  const int lane = tid & 63;             // owns j = {2*lane, 2*lane+1}

  // XCD-aware: all blocks of one batch on one XCD (L2 reuse of X)
  const int bid  = blockIdx.x;
  const int xcd  = bid & 7;
  const int slot = bid >> 3;
  const int b    = xcd + 8 * (slot & 1);
  const int rg   = slot >> 1;
  const int i    = rg * 8 + w;

  const float* __restrict__ Xb = X + (size_t)b * (LSEQ * D);
  float* __restrict__ Ob       = out + (size_t)b * (LSEQ * D);

  // per-lane state: mem row pair + opt pair (r2-verbatim)
  f2 m, o;
  m.x = init_mem[i * D + 2*lane];
  m.y = init_mem[i * D + 2*lane + 1];
  o.x = init_opt[i * D + 2*lane];
  o.y = init_opt[i * D + 2*lane + 1];
  f2 u;                                   // delta_i fold: e-dot uses (m - e_i)
  u.x = (2*lane     == i) ? 1.0f : 0.0f;
  u.y = (2*lane + 1 == i) ? 1.0f : 0.0f;

  // prologue: chunk 0 -> buf 0 (async direct-to-LDS)
  #pragma unroll
  for (int r = 0; r < 4; ++r)
    gl_lds16(Xb + (r*512 + tid)*4, &xs[0][(r*512 + tid)*4]);
  __syncthreads();

  for (int ch = 0; ch < NCHUNK; ++ch) {
    const int cur = ch & 1;

    // (a) coalesced store of previous chunk's outputs
    if (ch > 0) {
      const int c = tid >> 3, ww = tid & 7;
      Ob[(size_t)((ch-1)*CHK + c)*D + rg*8 + ww] = outs[cur ^ 1][c*9 + ww];
    }

    // (b) prefetch next chunk -> other buffer (in flight across whole compute)
    {
      int chn = ch + 1; if (chn >= NCHUNK) chn = NCHUNK - 1;
      const float* gb = Xb + (size_t)chn * (CHK * D);
      #pragma unroll
      for (int r = 0; r < 4; ++r)
        gl_lds16(gb + (r*512 + tid)*4, &xs[cur ^ 1][(r*512 + tid)*4]);
    }

    // (c) x[token=lane, i] gather from global (VMEM idle; L2-hot)
    const float xci = Xb[(size_t)(ch*CHK + lane)*D + i];

    f2 lr;
    lr.x = 1.0f / (1.0f + __expf(-o.x));
    lr.y = 1.0f / (1.0f + __expf(-o.y));
    const f2 mp = m - u;

    const float* xb = &xs[cur][2*lane];

    // (d) e-pass: partial dots -> butterfly => lane c holds e_c
    float arr[CHK];
    #pragma unroll
    for (int c = 0; c < CHK; ++c){
      f2 x2 = *(const f2*)(xb + c*D);      // ds_read_b64, stride 512B
      f2 t  = pk_mul(mp, x2);
      arr[c] = t.x + t.y;
    }
    const float e_own = butterfly64(arr, lane);
    {
      f2 ee; ee.x = e_own; ee.y = e_own;   // pre-splat: march needs {e,e} pairs
      es2[w][lane] = ee;                   // ds_write_b64, wave-private (in-order DS)
    }

    // (e) sequential token march, packed f32, zero marshaling:
    //     e broadcast comes pre-splatted from LDS; S,Q accumulate in place.
    f2 S; S.x = 0.f; S.y = 0.f;            // S is S' = lr .* cumsum(e x)
    f2 Q; Q.x = 0.f; Q.y = 0.f;
    #pragma unroll
    for (int c = 0; c < CHK; ++c){
      f2 e2 = es2[w][c];                   // ds_read_b64 (uniform addr -> broadcast)
      f2 x2 = *(const f2*)(xb + c*D);      // ds_read_b64
      f2 ex = pk_mul(e2, x2);
      pk_fma_acc(S, lr, ex);               // S += lr * e * x   (tied, in-place)
      f2 pt = pk_mul(x2, S);
      pk_fma_acc(Q, ex, ex);               // Q += (e x)^2      (tied, in-place)
      arr[c] = pt.x + pt.y;
    }
    const float p = butterfly64(arr, lane);  // lane c: p_c = sum_j lr_j x_cj S_cj

    // (f) out_c = dot(mem, x_c) - B_LR*p_c = e_c + x_ci - B_LR*p_c
    outs[cur][lane*9 + w] = e_own + xci - B_LR * p;

    // (g) chunk-end state update (r2-verbatim)
    m = m - B_LR * S;
    f2 g = lr - lr * lr;                   // lr*(1-lr)
    o = o - M_LR * (g * Q);

    // (h) single barrier: drains glds (next chunk ready), publishes outs
    __syncthreads();
  }

  // epilogue: final chunk's outputs
  {
    const int c = tid >> 3, ww = tid & 7;
    Ob[(size_t)((NCHUNK-1)*CHK + c)*D + rg*8 + ww] = outs[(NCHUNK-1)&1][c*9 + ww];
  }
}

extern "C" void kernel_launch(void* const* d_in, const int* in_sizes, int n_in,
                              void* d_out, int out_size, void* d_ws, size_t ws_size,
                              hipStream_t stream) {
    const float* X  = (const float*)d_in[0];
    const float* im = (const float*)d_in[1];
    const float* io = (const float*)d_in[2];
    float* O        = (float*)d_out;
    hipLaunchKernelGGL(lfltm_fwd, dim3(256), dim3(512), 0, stream, X, im, io, O);
}